// Round 1
// baseline (399.944 us; speedup 1.0000x reference)
//
#include <hip/hip_runtime.h>
#include <math.h>

// DeepOHeat_ST: 4 trunk MLPs + branch MLP, then rank-64 CP outer-product
// reconstruction out[b,i,j,k,l] = sum_z t0[i,z] t1[j,z] t2[k,z] t3[l,z] br[b,z]
//
// ws layout (floats):
//   t0T [z][i]  (64x64)  @ 0
//   t1T [z][j]  (64x64)  @ 4096
//   t2T [z][k]  (64x64)  @ 8192
//   t3T [z][l]  (64x32)  @ 12288
//   brT [z][b]  (64x8)   @ 14336
// total 14848 floats = 59392 bytes

#define HID 256
#define NFF 64

__global__ __launch_bounds__(256) void net_eval(
    const float* __restrict__ x1, const float* __restrict__ x2,
    const float* __restrict__ x3, const float* __restrict__ x4,
    const float* __restrict__ f,  const float* __restrict__ Bm,
    const float* __restrict__ tW0, const float* __restrict__ tb0,
    const float* __restrict__ tW1, const float* __restrict__ tb1,
    const float* __restrict__ tW2, const float* __restrict__ tb2,
    const float* __restrict__ tW3, const float* __restrict__ tb3,
    const float* __restrict__ bW0, const float* __restrict__ bb0,
    const float* __restrict__ bW1, const float* __restrict__ bb1,
    const float* __restrict__ bW2, const float* __restrict__ bb2,
    const float* __restrict__ bW3, const float* __restrict__ bb3,
    float* __restrict__ ws)
{
    __shared__ float bufA[HID];
    __shared__ float bufB[HID];
    const int t = threadIdx.x;
    const int bid = blockIdx.x;

    int net, row;
    if (bid < 192)      { net = bid >> 6; row = bid & 63; }
    else if (bid < 224) { net = 3;        row = bid - 192; }
    else                { net = 4;        row = bid - 224; }

    const float *W0, *B0v, *W1, *B1v, *W2, *B2v, *W3, *B3v;
    int in0;
    if (net < 4) {
        W0 = tW0 + (size_t)net * HID * 2 * NFF; B0v = tb0 + net * HID;
        W1 = tW1 + (size_t)net * HID * HID;     B1v = tb1 + net * HID;
        W2 = tW2 + (size_t)net * HID * HID;     B2v = tb2 + net * HID;
        W3 = tW3 + (size_t)net * 64 * HID;      B3v = tb3 + net * 64;
        in0 = 2 * NFF;
        const float* xp = (net == 0) ? x1 : (net == 1) ? x2 : (net == 2) ? x3 : x4;
        float xv = xp[row];
        if (t < 128) {
            float p = xv * Bm[t & 63];
            bufA[t] = (t < 64) ? cosf(p) : sinf(p);
        }
    } else {
        W0 = bW0; B0v = bb0; W1 = bW1; B1v = bb1;
        W2 = bW2; B2v = bb2; W3 = bW3; B3v = bb3;
        in0 = 256;
        bufA[t] = f[(size_t)row * 256 + t];
    }
    __syncthreads();

    // L0: bufA(in0) -> bufB  (swish)
    {
        float acc = B0v[t];
        const float4* wr = (const float4*)(W0 + (size_t)t * in0);
        const float4* iv = (const float4*)bufA;
        const int n4 = in0 >> 2;
        for (int k = 0; k < n4; ++k) {
            float4 w = wr[k]; float4 v = iv[k];
            acc += w.x * v.x + w.y * v.y + w.z * v.z + w.w * v.w;
        }
        bufB[t] = acc / (1.0f + expf(-acc));
    }
    __syncthreads();

    // L1: bufB(256) -> bufA  (swish)
    {
        float acc = B1v[t];
        const float4* wr = (const float4*)(W1 + (size_t)t * HID);
        const float4* iv = (const float4*)bufB;
        for (int k = 0; k < HID / 4; ++k) {
            float4 w = wr[k]; float4 v = iv[k];
            acc += w.x * v.x + w.y * v.y + w.z * v.z + w.w * v.w;
        }
        bufA[t] = acc / (1.0f + expf(-acc));
    }
    __syncthreads();

    // L2: bufA(256) -> bufB  (swish)
    {
        float acc = B2v[t];
        const float4* wr = (const float4*)(W2 + (size_t)t * HID);
        const float4* iv = (const float4*)bufA;
        for (int k = 0; k < HID / 4; ++k) {
            float4 w = wr[k]; float4 v = iv[k];
            acc += w.x * v.x + w.y * v.y + w.z * v.z + w.w * v.w;
        }
        bufB[t] = acc / (1.0f + expf(-acc));
    }
    __syncthreads();

    // L3: bufB(256) -> 64 outputs, stored transposed into ws
    if (t < 64) {
        float acc = B3v[t];
        const float4* wr = (const float4*)(W3 + (size_t)t * HID);
        const float4* iv = (const float4*)bufB;
        for (int k = 0; k < HID / 4; ++k) {
            float4 w = wr[k]; float4 v = iv[k];
            acc += w.x * v.x + w.y * v.y + w.z * v.z + w.w * v.w;
        }
        int base, stride;
        if      (net == 0) { base = 0;     stride = 64; }
        else if (net == 1) { base = 4096;  stride = 64; }
        else if (net == 2) { base = 8192;  stride = 64; }
        else if (net == 3) { base = 12288; stride = 32; }
        else               { base = 14336; stride = 8;  }
        ws[base + t * stride + row] = acc;
    }
}

// CP reconstruction. Grid: 8192 blocks = b(8) x i(64) x jtile(16). Block: 256
// threads = 4 waves, wave jj handles j = j0+jj. Each thread: 8 consecutive k
// x 4 consecutive l register tile, K-loop over z=0..63.
__global__ __launch_bounds__(256) void cp_recon(
    const float* __restrict__ ws, float* __restrict__ out)
{
    __shared__ float t2s[64 * 64];  // [z][k]
    __shared__ float t3s[64 * 32];  // [z][l]
    __shared__ float sS[4 * 64];    // [jj][z]

    const int t = threadIdx.x;
    const int bid = blockIdx.x;
    const int b  = bid >> 10;
    const int i  = (bid >> 4) & 63;
    const int j0 = (bid & 15) * 4;

    // stage t2T, t3T (straight copy: coalesced global, conflict-free LDS)
    #pragma unroll
    for (int m = 0; m < 16; ++m) {
        int g = t + m * 256;
        t2s[g] = ws[8192 + g];
    }
    #pragma unroll
    for (int m = 0; m < 8; ++m) {
        int g = t + m * 256;
        t3s[g] = ws[12288 + g];
    }
    // s[jj][z] = t0[i,z] * t1[j0+jj,z] * br[b,z]
    {
        int jj = t >> 6;
        int z  = t & 63;
        sS[t] = ws[z * 64 + i] * ws[4096 + z * 64 + j0 + jj] * ws[14336 + z * 8 + b];
    }
    __syncthreads();

    const int jj   = t >> 6;
    const int lane = t & 63;
    const int k0   = (lane >> 3) * 8;
    const int l0   = (lane & 7) * 4;
    const float* sp = &sS[jj * 64];

    float4 acc[8];
    #pragma unroll
    for (int kk = 0; kk < 8; ++kk) acc[kk] = make_float4(0.f, 0.f, 0.f, 0.f);

    #pragma unroll 4
    for (int z = 0; z < 64; ++z) {
        float sz = sp[z];
        float4 t3v = *(const float4*)&t3s[z * 32 + l0];
        float4 a0  = *(const float4*)&t2s[z * 64 + k0];
        float4 a1  = *(const float4*)&t2s[z * 64 + k0 + 4];
        float4 u;
        u.x = sz * t3v.x; u.y = sz * t3v.y; u.z = sz * t3v.z; u.w = sz * t3v.w;
        float ks0 = a0.x, ks1 = a0.y, ks2 = a0.z, ks3 = a0.w;
        float ks4 = a1.x, ks5 = a1.y, ks6 = a1.z, ks7 = a1.w;
        acc[0].x += ks0 * u.x; acc[0].y += ks0 * u.y; acc[0].z += ks0 * u.z; acc[0].w += ks0 * u.w;
        acc[1].x += ks1 * u.x; acc[1].y += ks1 * u.y; acc[1].z += ks1 * u.z; acc[1].w += ks1 * u.w;
        acc[2].x += ks2 * u.x; acc[2].y += ks2 * u.y; acc[2].z += ks2 * u.z; acc[2].w += ks2 * u.w;
        acc[3].x += ks3 * u.x; acc[3].y += ks3 * u.y; acc[3].z += ks3 * u.z; acc[3].w += ks3 * u.w;
        acc[4].x += ks4 * u.x; acc[4].y += ks4 * u.y; acc[4].z += ks4 * u.z; acc[4].w += ks4 * u.w;
        acc[5].x += ks5 * u.x; acc[5].y += ks5 * u.y; acc[5].z += ks5 * u.z; acc[5].w += ks5 * u.w;
        acc[6].x += ks6 * u.x; acc[6].y += ks6 * u.y; acc[6].z += ks6 * u.z; acc[6].w += ks6 * u.w;
        acc[7].x += ks7 * u.x; acc[7].y += ks7 * u.y; acc[7].z += ks7 * u.z; acc[7].w += ks7 * u.w;
    }

    // out[b][i][j][k][l], plane (k,l) = 2048 floats, contiguous
    size_t base = ((size_t)((b * 64 + i) * 64 + (j0 + jj))) * 2048;
    float* op = out + base;
    #pragma unroll
    for (int kk = 0; kk < 8; ++kk) {
        *(float4*)&op[(k0 + kk) * 32 + l0] = acc[kk];
    }
}

extern "C" void kernel_launch(void* const* d_in, const int* in_sizes, int n_in,
                              void* d_out, int out_size, void* d_ws, size_t ws_size,
                              hipStream_t stream) {
    const float* x1  = (const float*)d_in[0];
    const float* x2  = (const float*)d_in[1];
    const float* x3  = (const float*)d_in[2];
    const float* x4  = (const float*)d_in[3];
    const float* f   = (const float*)d_in[4];
    const float* Bm  = (const float*)d_in[5];
    const float* tW0 = (const float*)d_in[6];
    const float* tb0 = (const float*)d_in[7];
    const float* tW1 = (const float*)d_in[8];
    const float* tb1 = (const float*)d_in[9];
    const float* tW2 = (const float*)d_in[10];
    const float* tb2 = (const float*)d_in[11];
    const float* tW3 = (const float*)d_in[12];
    const float* tb3 = (const float*)d_in[13];
    const float* bW0 = (const float*)d_in[14];
    const float* bb0 = (const float*)d_in[15];
    const float* bW1 = (const float*)d_in[16];
    const float* bb1 = (const float*)d_in[17];
    const float* bW2 = (const float*)d_in[18];
    const float* bb2 = (const float*)d_in[19];
    const float* bW3 = (const float*)d_in[20];
    const float* bb3 = (const float*)d_in[21];

    float* ws  = (float*)d_ws;
    float* out = (float*)d_out;

    hipLaunchKernelGGL(net_eval, dim3(232), dim3(256), 0, stream,
                       x1, x2, x3, x4, f, Bm,
                       tW0, tb0, tW1, tb1, tW2, tb2, tW3, tb3,
                       bW0, bb0, bW1, bb1, bW2, bb2, bW3, bb3, ws);
    hipLaunchKernelGGL(cp_recon, dim3(8192), dim3(256), 0, stream, ws, out);
}